// Round 1
// baseline (177.032 us; speedup 1.0000x reference)
//
#include <hip/hip_runtime.h>

typedef __bf16 bf16;
typedef __attribute__((ext_vector_type(8))) __bf16 bf16x8;
typedef __attribute__((ext_vector_type(4))) __bf16 bf16x4;
typedef __attribute__((ext_vector_type(4))) float f32x4;

#define MFMA(a, b, c) __builtin_amdgcn_mfma_f32_16x16x32_bf16((a), (b), (c), 0, 0, 0)
#define LOG2E 1.44269504088896340736f

__device__ __forceinline__ bf16x8 cvt8(float4 a, float4 b) {
  bf16x8 r;
  r[0] = (bf16)a.x; r[1] = (bf16)a.y; r[2] = (bf16)a.z; r[3] = (bf16)a.w;
  r[4] = (bf16)b.x; r[5] = (bf16)b.y; r[6] = (bf16)b.z; r[7] = (bf16)b.w;
  return r;
}

// async global->LDS, 16B per lane. LDS dest = wave-uniform base + lane*16.
__device__ __forceinline__ void stage16(const bf16* g, bf16* l) {
  __builtin_amdgcn_global_load_lds(
      (const __attribute__((address_space(1))) void*)g,
      (__attribute__((address_space(3))) void*)l, 16, 0, 0);
}

// ---------------------------------------------------------------------------
// Kernel 0: cast X -> bf16; cast+transpose W -> bf16 W^T[n][k] (3 matrices).
// ---------------------------------------------------------------------------
__global__ __launch_bounds__(256)
void cvt(const float* __restrict__ hs, const float* __restrict__ qw,
         const float* __restrict__ kw, const float* __restrict__ vw,
         bf16* __restrict__ Xb, bf16* __restrict__ Wt) {
  const int bid = blockIdx.x, tid = threadIdx.x;
  if (bid < 2048) {               // X: 4096x1024 fp32 -> bf16, 8 elems/thread
    size_t off = (size_t)bid * 2048 + tid * 8;
    float4 x0 = *(const float4*)(hs + off);
    float4 x1 = *(const float4*)(hs + off + 4);
    *(bf16x8*)(Xb + off) = cvt8(x0, x1);
  } else {                        // W transpose: 64x64 tiles via LDS
    int t = bid - 2048;           // 0..767
    int z = t >> 8, ti = t & 255;
    const float* W = (z == 0) ? qw : (z == 1) ? kw : vw;
    int k0 = (ti >> 4) * 64, n0 = (ti & 15) * 64;
    __shared__ bf16 T[64 * 72];   // [n][k], pad 72 (16B-aligned rows)
    #pragma unroll
    for (int i = 0; i < 16; ++i) {
      int e = i * 256 + tid;
      int kr = e >> 6, nc = e & 63;
      T[nc * 72 + kr] = (bf16)W[(size_t)(k0 + kr) * 1024 + n0 + nc];
    }
    __syncthreads();
    #pragma unroll
    for (int i = 0; i < 2; ++i) {
      int e = i * 256 + tid;
      int nr = e >> 3, kg = e & 7;
      *(bf16x8*)(Wt + (size_t)z * 1048576 + (size_t)(n0 + nr) * 1024 + k0 + kg * 8) =
          *(const bf16x8*)&T[nr * 72 + kg * 8];
    }
  }
}

// ---------------------------------------------------------------------------
// Kernel 1: QKV GEMM (m97-style). 128x128 tile, 4 waves 2x2, BK=64,
// global_load_lds w=16, XOR-granule swizzle on the global-address side.
// Q pre-scaled by 0.125*log2e. V written TRANSPOSED [B,H,64,S].
// ---------------------------------------------------------------------------
__global__ __launch_bounds__(256, 3)
void qkv_gemm(const bf16* __restrict__ Xb, const bf16* __restrict__ Wt,
              const float* __restrict__ qbias, const float* __restrict__ kbias,
              const float* __restrict__ vbias,
              bf16* __restrict__ qo, bf16* __restrict__ ko, bf16* __restrict__ vo) {
  const int blk = blockIdx.x;           // 0..767
  const int xcd = blk & 7, slot = blk >> 3;   // slot 0..95
  const int mb = xcd * 4 + slot / 24;   // 0..31 (mb-band per XCD)
  const int nb = slot % 24;             // 0..23
  const int z = nb >> 3, nbm = nb & 7;
  const bf16* W = Wt + (size_t)z * 1048576;

  const int tid = threadIdx.x;
  const int wave = tid >> 6, lane = tid & 63, quad = lane >> 4, c = lane & 15;
  const int wr = wave >> 1, wc = wave & 1;
  const int lrow = lane >> 3;                 // 0..7 within the 8-row group
  const int lg = (lane & 7) ^ lrow;           // swizzled source granule

  __shared__ bf16 As[128 * 64];               // [m][k], granule g at pos g^(m&7)
  __shared__ bf16 Bs[128 * 64];               // [n][k], same swizzle

  f32x4 acc[4][4] = {};

  for (int k0 = 0; k0 < 1024; k0 += 64) {
    #pragma unroll
    for (int i = 0; i < 4; ++i) {
      int r = wave * 32 + i * 8;              // base row (mult of 8)
      stage16(Xb + (size_t)(mb * 128 + r + lrow) * 1024 + k0 + lg * 8, &As[r * 64]);
      stage16(W + (size_t)(nbm * 128 + r + lrow) * 1024 + k0 + lg * 8, &Bs[r * 64]);
    }
    __syncthreads();
    #pragma unroll
    for (int ch = 0; ch < 2; ++ch) {
      bf16x8 af[4];
      #pragma unroll
      for (int rt = 0; rt < 4; ++rt) {
        int row = wr * 64 + rt * 16 + c;      // row&7 == c&7
        af[rt] = *(const bf16x8*)&As[row * 64 + ((((ch << 2) | quad) ^ (c & 7)) << 3)];
      }
      #pragma unroll
      for (int nt = 0; nt < 4; ++nt) {
        int row = wc * 64 + nt * 16 + c;
        bf16x8 bfrag = *(const bf16x8*)&Bs[row * 64 + ((((ch << 2) | quad) ^ (c & 7)) << 3)];
        #pragma unroll
        for (int rt = 0; rt < 4; ++rt)
          acc[rt][nt] = MFMA(af[rt], bfrag, acc[rt][nt]);
      }
    }
    __syncthreads();
  }

  const float* bias = (z == 0) ? qbias : (z == 1) ? kbias : vbias;
  float bv[4];
  #pragma unroll
  for (int nt = 0; nt < 4; ++nt)
    bv[nt] = bias[nbm * 128 + wc * 64 + nt * 16 + c];

  if (z == 2) {
    // V^T: vo[((b*16+h)*64 + d)*2048 + s], packed 4 along s (= reg dim)
    #pragma unroll
    for (int rt = 0; rt < 4; ++rt)
      #pragma unroll
      for (int nt = 0; nt < 4; ++nt) {
        int m0 = mb * 128 + wr * 64 + rt * 16 + 4 * quad;
        int n = nbm * 128 + wc * 64 + nt * 16 + c;
        bf16x4 pk;
        #pragma unroll
        for (int reg = 0; reg < 4; ++reg) pk[reg] = (bf16)(acc[rt][nt][reg] + bv[nt]);
        int b = m0 >> 11, s0 = m0 & 2047, h = n >> 6, d = n & 63;
        *(bf16x4*)&vo[(((size_t)b * 16 + h) * 64 + d) * 2048 + s0] = pk;
      }
  } else {
    bf16* dst = (z == 0) ? qo : ko;
    const float scale = (z == 0) ? 0.125f * LOG2E : 1.0f;  // fold 1/sqrt(d)*log2e into Q
    #pragma unroll
    for (int rt = 0; rt < 4; ++rt)
      #pragma unroll
      for (int nt = 0; nt < 4; ++nt)
        #pragma unroll
        for (int reg = 0; reg < 4; ++reg) {
          float v = (acc[rt][nt][reg] + bv[nt]) * scale;
          int m = mb * 128 + wr * 64 + rt * 16 + 4 * quad + reg;
          int n = nbm * 128 + wc * 64 + nt * 16 + c;
          int b = m >> 11, s = m & 2047, h = n >> 6, d = n & 63;
          dst[(((size_t)b * 16 + h) * 2048 + s) * 64 + d] = (bf16)v;
        }
  }
}

// ---------------------------------------------------------------------------
// Kernel 2: attention, swapped-QK^T (S^T: row=key, col=q) + double-buffered
// async K/V staging, ONE raw s_barrier per kt-iter (counted-drain recipe):
//   issue stage(kt+1) -> compute S^T from buf[cur] -> vectorized P spill
//   (4x ds_write_b64 vs 16x b16) -> PV as MFMA(V-frag, P-frag) -> O^T ->
//   s_waitcnt vmcnt(0) lgkmcnt(0); s_barrier.
// Swapped layout also gives: per-lane scalar lsum (2 shfl_xor reduce),
// float4 mask loads, float4 epilogue stores.
// 512 threads, 8 waves x 16 q-rows; 512 WGs -> 2 blocks/CU. LDS 48KB.
// ---------------------------------------------------------------------------
__global__ __launch_bounds__(512, 4)
void attn(const bf16* __restrict__ qg, const bf16* __restrict__ kg,
          const bf16* __restrict__ vtg, const float* __restrict__ mask,
          float* __restrict__ out) {
  const int blk = blockIdx.x;                // 0..511
  const int xcd = blk & 7, slot = blk >> 3;  // slot 0..63
  const int bh = xcd * 4 + (slot >> 4);      // 4 bh per XCD (K/V pinned in L2)
  const int qblk = slot & 15;
  const int b = bh >> 4, h = bh & 15;
  const int tid = threadIdx.x;
  const int wave = tid >> 6, lane = tid & 63, quad = lane >> 4, c = lane & 15;
  const int lrow = lane >> 3, lg = (lane & 7) ^ lrow;

  __shared__ bf16 Ks[2][64 * 64];   // [key][d], granule g at pos g^(key&7)
  __shared__ bf16 Vs[2][64 * 64];   // [d][key], same swizzle
  __shared__ bf16 Ps[8][1024];      // per-wave P[q=c][key], swizzled granules

  const bf16* qb_ = qg + (size_t)bh * 2048 * 64;
  const bf16* kb_ = kg + (size_t)bh * 2048 * 64;
  const bf16* vb_ = vtg + (size_t)bh * 64 * 2048;

  bf16x8 qf[2];   // Q pre-scaled by 0.125*log2e; wave owns rows wave*16..+15
  #pragma unroll
  for (int ch = 0; ch < 2; ++ch)
    qf[ch] = *(const bf16x8*)(qb_ +
        (size_t)(qblk * 128 + wave * 16 + c) * 64 + ch * 32 + quad * 8);

  f32x4 o[4] = {};                  // O^T: o[nt][reg] = O[q=c][d=nt*16+4*quad+reg]
  float lsum = 0.f;                 // per-lane partial over this lane's 16 keys

  // ---- prologue: stage tile 0 ----
  {
    int r = wave * 8;
    stage16(kb_ + (size_t)(r + lrow) * 64 + lg * 8, &Ks[0][r * 64]);
    stage16(vb_ + (size_t)(r + lrow) * 2048 + lg * 8, &Vs[0][r * 64]);
  }
  __asm__ volatile("s_waitcnt vmcnt(0)" ::: "memory");
  __builtin_amdgcn_s_barrier();

  for (int kt = 0; kt < 32; ++kt) {
    const int cur = kt & 1;

    // ---- issue next tile's async loads; they fly under this iter's compute
    if (kt < 31) {
      int r = wave * 8;
      stage16(kb_ + (size_t)((kt + 1) * 64 + r + lrow) * 64 + lg * 8,
              &Ks[cur ^ 1][r * 64]);
      stage16(vb_ + (size_t)(r + lrow) * 2048 + (kt + 1) * 64 + lg * 8,
              &Vs[cur ^ 1][r * 64]);
    }
    __builtin_amdgcn_sched_barrier(0);  // pin: loads issued before compute

    // ---- S^T = K Q^T (A=K-frag, B=Q-frag; same register data, swapped role)
    f32x4 s[4] = {};
    #pragma unroll
    for (int nt = 0; nt < 4; ++nt)
      #pragma unroll
      for (int ch = 0; ch < 2; ++ch) {
        bf16x8 kf = *(const bf16x8*)&Ks[cur][(nt * 16 + c) * 64 +
                                            ((((ch << 2) | quad) ^ (c & 7)) << 3)];
        s[nt] = MFMA(kf, qf[ch], s[nt]);
      }

    // ---- p = exp2(s + mask); lane holds keys nt*16+4*quad+reg for q=c.
    // Spill P[q=c][key] with 4x b64 vectorized swizzled writes.
    #pragma unroll
    for (int nt = 0; nt < 4; ++nt) {
      float4 mv = *(const float4*)&mask[b * 2048 + kt * 64 + nt * 16 + 4 * quad];
      bf16x4 pk;
      #pragma unroll
      for (int reg = 0; reg < 4; ++reg) {
        float mreg = (reg == 0) ? mv.x : (reg == 1) ? mv.y : (reg == 2) ? mv.z : mv.w;
        float p = __builtin_amdgcn_exp2f(s[nt][reg] + mreg * LOG2E);
        lsum += p;
        pk[reg] = (bf16)p;
      }
      int g = (nt * 2 + (quad >> 1)) ^ (c & 7);          // 16B-granule swizzle
      *(bf16x4*)&Ps[wave][c * 64 + g * 8 + (quad & 1) * 4] = pk;
    }
    __asm__ volatile("s_waitcnt lgkmcnt(0)" ::: "memory");  // wave-private order

    // ---- O^T += V^T P^T  (A=V-frag, B=P-frag)
    #pragma unroll
    for (int ch = 0; ch < 2; ++ch) {
      bf16x8 pa = *(const bf16x8*)&Ps[wave][c * 64 +
                                           ((((ch << 2) | quad) ^ (c & 7)) << 3)];
      #pragma unroll
      for (int nt = 0; nt < 4; ++nt) {
        bf16x8 vf = *(const bf16x8*)&Vs[cur][(nt * 16 + c) * 64 +
                                            ((((ch << 2) | quad) ^ (c & 7)) << 3)];
        o[nt] = MFMA(vf, pa, o[nt]);
      }
    }

    // ---- single drain + barrier: next-tile loads done, this tile's reads done
    __asm__ volatile("s_waitcnt vmcnt(0) lgkmcnt(0)" ::: "memory");
    __builtin_amdgcn_s_barrier();
  }

  // ---- l reduce over the 4 quads sharing q=c, normalize, float4 store ----
  lsum += __shfl_xor(lsum, 16, 64);
  lsum += __shfl_xor(lsum, 32, 64);
  const float inv = 1.0f / lsum;

  const int srow = qblk * 128 + wave * 16 + c;
  #pragma unroll
  for (int nt = 0; nt < 4; ++nt) {
    float4 st = { o[nt][0] * inv, o[nt][1] * inv, o[nt][2] * inv, o[nt][3] * inv };
    *(float4*)&out[((size_t)b * 2048 + srow) * 1024 + h * 64 + nt * 16 + 4 * quad] = st;
  }
}

// ---------------------------------------------------------------------------
extern "C" void kernel_launch(void* const* d_in, const int* in_sizes, int n_in,
                              void* d_out, int out_size, void* d_ws, size_t ws_size,
                              hipStream_t stream) {
  const float* hs   = (const float*)d_in[0];
  const float* mask = (const float*)d_in[1];
  const float* qw   = (const float*)d_in[2];
  const float* qb   = (const float*)d_in[3];
  const float* kw   = (const float*)d_in[4];
  const float* kb   = (const float*)d_in[5];
  const float* vw   = (const float*)d_in[6];
  const float* vb   = (const float*)d_in[7];
  float* out = (float*)d_out;

  bf16* Xb   = (bf16*)d_ws;                       // 4096x1024      (8 MB)
  bf16* Wt   = Xb + (size_t)4096 * 1024;          // 3x1024x1024    (6 MB)
  bf16* q_ws = Wt + (size_t)3 * 1048576;          // [B,H,S,64]     (8 MB)
  bf16* k_ws = q_ws + (size_t)4096 * 1024;        // [B,H,S,64]     (8 MB)
  bf16* v_ws = k_ws + (size_t)4096 * 1024;        // [B,H,64,S] V^T (8 MB)

  cvt<<<dim3(2816), 256, 0, stream>>>(hs, qw, kw, vw, Xb, Wt);
  qkv_gemm<<<dim3(768), 256, 0, stream>>>(Xb, Wt, qb, kb, vb, q_ws, k_ws, v_ws);
  attn<<<dim3(512), 512, 0, stream>>>(q_ws, k_ws, v_ws, mask, out);
}

// Round 2
// 176.860 us; speedup vs baseline: 1.0010x; 1.0010x over previous
//
#include <hip/hip_runtime.h>

typedef __bf16 bf16;
typedef __attribute__((ext_vector_type(8))) __bf16 bf16x8;
typedef __attribute__((ext_vector_type(4))) __bf16 bf16x4;
typedef __attribute__((ext_vector_type(4))) float f32x4;

#define MFMA(a, b, c) __builtin_amdgcn_mfma_f32_16x16x32_bf16((a), (b), (c), 0, 0, 0)
#define LOG2E 1.44269504088896340736f

__device__ __forceinline__ bf16x8 cvt8(float4 a, float4 b) {
  bf16x8 r;
  r[0] = (bf16)a.x; r[1] = (bf16)a.y; r[2] = (bf16)a.z; r[3] = (bf16)a.w;
  r[4] = (bf16)b.x; r[5] = (bf16)b.y; r[6] = (bf16)b.z; r[7] = (bf16)b.w;
  return r;
}

// async global->LDS, 16B per lane. LDS dest = wave-uniform base + lane*16.
__device__ __forceinline__ void stage16(const bf16* g, bf16* l) {
  __builtin_amdgcn_global_load_lds(
      (const __attribute__((address_space(1))) void*)g,
      (__attribute__((address_space(3))) void*)l, 16, 0, 0);
}

// ---------------------------------------------------------------------------
// Kernel 0: cast X -> bf16; cast+transpose W -> bf16 W^T[n][k] (3 matrices).
// ---------------------------------------------------------------------------
__global__ __launch_bounds__(256)
void cvt(const float* __restrict__ hs, const float* __restrict__ qw,
         const float* __restrict__ kw, const float* __restrict__ vw,
         bf16* __restrict__ Xb, bf16* __restrict__ Wt) {
  const int bid = blockIdx.x, tid = threadIdx.x;
  if (bid < 2048) {               // X: 4096x1024 fp32 -> bf16, 8 elems/thread
    size_t off = (size_t)bid * 2048 + tid * 8;
    float4 x0 = *(const float4*)(hs + off);
    float4 x1 = *(const float4*)(hs + off + 4);
    *(bf16x8*)(Xb + off) = cvt8(x0, x1);
  } else {                        // W transpose: 64x64 tiles via LDS
    int t = bid - 2048;           // 0..767
    int z = t >> 8, ti = t & 255;
    const float* W = (z == 0) ? qw : (z == 1) ? kw : vw;
    int k0 = (ti >> 4) * 64, n0 = (ti & 15) * 64;
    __shared__ bf16 T[64 * 72];   // [n][k], pad 72 (16B-aligned rows)
    #pragma unroll
    for (int i = 0; i < 16; ++i) {
      int e = i * 256 + tid;
      int kr = e >> 6, nc = e & 63;
      T[nc * 72 + kr] = (bf16)W[(size_t)(k0 + kr) * 1024 + n0 + nc];
    }
    __syncthreads();
    #pragma unroll
    for (int i = 0; i < 2; ++i) {
      int e = i * 256 + tid;
      int nr = e >> 3, kg = e & 7;
      *(bf16x8*)(Wt + (size_t)z * 1048576 + (size_t)(n0 + nr) * 1024 + k0 + kg * 8) =
          *(const bf16x8*)&T[nr * 72 + kg * 8];
    }
  }
}

// ---------------------------------------------------------------------------
// Kernel 1: QKV GEMM (m97-style). 128x128 tile, 4 waves 2x2, BK=64,
// global_load_lds w=16, XOR-granule swizzle on the global-address side.
// Q pre-scaled by 0.125*log2e. V written TRANSPOSED [B,H,64,S].
// ---------------------------------------------------------------------------
__global__ __launch_bounds__(256, 3)
void qkv_gemm(const bf16* __restrict__ Xb, const bf16* __restrict__ Wt,
              const float* __restrict__ qbias, const float* __restrict__ kbias,
              const float* __restrict__ vbias,
              bf16* __restrict__ qo, bf16* __restrict__ ko, bf16* __restrict__ vo) {
  const int blk = blockIdx.x;           // 0..767
  const int xcd = blk & 7, slot = blk >> 3;   // slot 0..95
  const int mb = xcd * 4 + slot / 24;   // 0..31 (mb-band per XCD)
  const int nb = slot % 24;             // 0..23
  const int z = nb >> 3, nbm = nb & 7;
  const bf16* W = Wt + (size_t)z * 1048576;

  const int tid = threadIdx.x;
  const int wave = tid >> 6, lane = tid & 63, quad = lane >> 4, c = lane & 15;
  const int wr = wave >> 1, wc = wave & 1;
  const int lrow = lane >> 3;                 // 0..7 within the 8-row group
  const int lg = (lane & 7) ^ lrow;           // swizzled source granule

  __shared__ bf16 As[128 * 64];               // [m][k], granule g at pos g^(m&7)
  __shared__ bf16 Bs[128 * 64];               // [n][k], same swizzle

  f32x4 acc[4][4] = {};

  for (int k0 = 0; k0 < 1024; k0 += 64) {
    #pragma unroll
    for (int i = 0; i < 4; ++i) {
      int r = wave * 32 + i * 8;              // base row (mult of 8)
      stage16(Xb + (size_t)(mb * 128 + r + lrow) * 1024 + k0 + lg * 8, &As[r * 64]);
      stage16(W + (size_t)(nbm * 128 + r + lrow) * 1024 + k0 + lg * 8, &Bs[r * 64]);
    }
    __syncthreads();
    #pragma unroll
    for (int ch = 0; ch < 2; ++ch) {
      bf16x8 af[4];
      #pragma unroll
      for (int rt = 0; rt < 4; ++rt) {
        int row = wr * 64 + rt * 16 + c;      // row&7 == c&7
        af[rt] = *(const bf16x8*)&As[row * 64 + ((((ch << 2) | quad) ^ (c & 7)) << 3)];
      }
      #pragma unroll
      for (int nt = 0; nt < 4; ++nt) {
        int row = wc * 64 + nt * 16 + c;
        bf16x8 bfrag = *(const bf16x8*)&Bs[row * 64 + ((((ch << 2) | quad) ^ (c & 7)) << 3)];
        #pragma unroll
        for (int rt = 0; rt < 4; ++rt)
          acc[rt][nt] = MFMA(af[rt], bfrag, acc[rt][nt]);
      }
    }
    __syncthreads();
  }

  const float* bias = (z == 0) ? qbias : (z == 1) ? kbias : vbias;
  float bv[4];
  #pragma unroll
  for (int nt = 0; nt < 4; ++nt)
    bv[nt] = bias[nbm * 128 + wc * 64 + nt * 16 + c];

  if (z == 2) {
    // V^T: vo[((b*16+h)*64 + d)*2048 + s], packed 4 along s (= reg dim)
    #pragma unroll
    for (int rt = 0; rt < 4; ++rt)
      #pragma unroll
      for (int nt = 0; nt < 4; ++nt) {
        int m0 = mb * 128 + wr * 64 + rt * 16 + 4 * quad;
        int n = nbm * 128 + wc * 64 + nt * 16 + c;
        bf16x4 pk;
        #pragma unroll
        for (int reg = 0; reg < 4; ++reg) pk[reg] = (bf16)(acc[rt][nt][reg] + bv[nt]);
        int b = m0 >> 11, s0 = m0 & 2047, h = n >> 6, d = n & 63;
        *(bf16x4*)&vo[(((size_t)b * 16 + h) * 64 + d) * 2048 + s0] = pk;
      }
  } else {
    bf16* dst = (z == 0) ? qo : ko;
    const float scale = (z == 0) ? 0.125f * LOG2E : 1.0f;  // fold 1/sqrt(d)*log2e into Q
    #pragma unroll
    for (int rt = 0; rt < 4; ++rt)
      #pragma unroll
      for (int nt = 0; nt < 4; ++nt)
        #pragma unroll
        for (int reg = 0; reg < 4; ++reg) {
          float v = (acc[rt][nt][reg] + bv[nt]) * scale;
          int m = mb * 128 + wr * 64 + rt * 16 + 4 * quad + reg;
          int n = nbm * 128 + wc * 64 + nt * 16 + c;
          int b = m >> 11, s = m & 2047, h = n >> 6, d = n & 63;
          dst[(((size_t)b * 16 + h) * 2048 + s) * 64 + d] = (bf16)v;
        }
  }
}

// ---------------------------------------------------------------------------
// Kernel 2: attention. LDS-throughput-bound analysis: each wave must read the
// full K and V tile regardless of q-rows owned, so amortize by widening to
// 32 q-rows/wave (2 column-tiles). 4-wave WGs (256 thr) x 512 WGs = 2 WG/CU,
// 8 waves/CU. Per wave-iter: 8 kf + 8 vf b128 reads now feed 32 MFMAs (was
// 16) -> LDS demand per unit work halves (~74K cyc/CU total, ~31us floor).
// P buffer: row stride 136B (34 dwords == 2 banks/row rotation) ->
// write b64 banks (2c+4g+2h)%32 bijective over 16-lane groups: 0 conflicts.
// pa read as 2x ds_read_b64 (136B rows are 8B- not 16B-aligned).
// Double-buffered async K/V staging, one s_barrier per iter.
// ---------------------------------------------------------------------------
__global__ __launch_bounds__(256, 2)
void attn(const bf16* __restrict__ qg, const bf16* __restrict__ kg,
          const bf16* __restrict__ vtg, const float* __restrict__ mask,
          float* __restrict__ out) {
  const int blk = blockIdx.x;                // 0..511
  const int xcd = blk & 7, slot = blk >> 3;  // slot 0..63
  const int bh = xcd * 4 + (slot >> 4);      // 4 bh per XCD (K/V pinned in L2)
  const int qblk = slot & 15;                // 16 qblks x 128 rows
  const int b = bh >> 4, h = bh & 15;
  const int tid = threadIdx.x;
  const int wave = tid >> 6, lane = tid & 63, quad = lane >> 4, c = lane & 15;
  const int lrow = lane >> 3, lg = (lane & 7) ^ lrow;

  __shared__ __align__(16) bf16 Ks[2][64 * 64];  // [key][d], granule swizzle
  __shared__ __align__(16) bf16 Vs[2][64 * 64];  // [d][key], granule swizzle
  __shared__ __align__(16) bf16 Ps[4][2][16 * 68];  // [wave][ct], stride 68 elems

  const bf16* qb_ = qg + (size_t)bh * 2048 * 64;
  const bf16* kb_ = kg + (size_t)bh * 2048 * 64;
  const bf16* vb_ = vtg + (size_t)bh * 64 * 2048;

  // Q (pre-scaled by 0.125*log2e): wave owns q-rows wave*32 + ct*16 + c
  bf16x8 qf[2][2];
  #pragma unroll
  for (int ct = 0; ct < 2; ++ct)
    #pragma unroll
    for (int ch = 0; ch < 2; ++ch)
      qf[ct][ch] = *(const bf16x8*)(qb_ +
          (size_t)(qblk * 128 + wave * 32 + ct * 16 + c) * 64 + ch * 32 + quad * 8);

  f32x4 o[2][4] = {};     // o[ct][nt][reg] = O[q = ct*16+c][d = nt*16+4*quad+reg]
  float lsum[2] = {0.f, 0.f};

  // ---- prologue: stage tile 0 (wave stages 16 K rows + 16 V rows) ----
  #pragma unroll
  for (int i = 0; i < 2; ++i) {
    int r = wave * 16 + i * 8;
    stage16(kb_ + (size_t)(r + lrow) * 64 + lg * 8, &Ks[0][r * 64]);
    stage16(vb_ + (size_t)(r + lrow) * 2048 + lg * 8, &Vs[0][r * 64]);
  }
  __asm__ volatile("s_waitcnt vmcnt(0)" ::: "memory");
  __builtin_amdgcn_s_barrier();

  for (int kt = 0; kt < 32; ++kt) {
    const int cur = kt & 1;

    // ---- issue next tile's async loads; fly under this iter's compute ----
    if (kt < 31) {
      #pragma unroll
      for (int i = 0; i < 2; ++i) {
        int r = wave * 16 + i * 8;
        stage16(kb_ + (size_t)((kt + 1) * 64 + r + lrow) * 64 + lg * 8,
                &Ks[cur ^ 1][r * 64]);
        stage16(vb_ + (size_t)(r + lrow) * 2048 + (kt + 1) * 64 + lg * 8,
                &Vs[cur ^ 1][r * 64]);
      }
    }
    __builtin_amdgcn_sched_barrier(0);  // pin: loads issued before compute

    // ---- mask (key-only, shared across ct) ----
    float4 mv[4];
    #pragma unroll
    for (int nt = 0; nt < 4; ++nt)
      mv[nt] = *(const float4*)&mask[b * 2048 + kt * 64 + nt * 16 + 4 * quad];

    // ---- S^T = K Q^T: kf loaded once per (nt,ch), reused for both ct ----
    f32x4 s[2][4] = {};
    #pragma unroll
    for (int nt = 0; nt < 4; ++nt)
      #pragma unroll
      for (int ch = 0; ch < 2; ++ch) {
        bf16x8 kf = *(const bf16x8*)&Ks[cur][(nt * 16 + c) * 64 +
                                            ((((ch << 2) | quad) ^ (c & 7)) << 3)];
        #pragma unroll
        for (int ct = 0; ct < 2; ++ct)
          s[ct][nt] = MFMA(kf, qf[ct][ch], s[ct][nt]);
      }

    // ---- p = exp2(s + mask); spill P[q=c][key] as b64, 136B row stride ----
    #pragma unroll
    for (int ct = 0; ct < 2; ++ct)
      #pragma unroll
      for (int nt = 0; nt < 4; ++nt) {
        bf16x4 pk;
        #pragma unroll
        for (int reg = 0; reg < 4; ++reg) {
          float mreg = (reg == 0) ? mv[nt].x : (reg == 1) ? mv[nt].y
                     : (reg == 2) ? mv[nt].z : mv[nt].w;
          float p = __builtin_amdgcn_exp2f(s[ct][nt][reg] + mreg * LOG2E);
          lsum[ct] += p;
          pk[reg] = (bf16)p;
        }
        int g = (nt * 2 + (quad >> 1)) ^ (c & 7);
        *(bf16x4*)&Ps[wave][ct][c * 68 + g * 8 + (quad & 1) * 4] = pk;
      }
    __asm__ volatile("s_waitcnt lgkmcnt(0)" ::: "memory");  // wave-private order

    // ---- O^T += V^T P^T: vf loaded once per (nt,ch), reused for both ct ----
    #pragma unroll
    for (int ch = 0; ch < 2; ++ch) {
      bf16x8 pa[2];
      #pragma unroll
      for (int ct = 0; ct < 2; ++ct) {
        int gp = ((ch << 2) | quad) ^ (c & 7);
        bf16x4 lo = *(const bf16x4*)&Ps[wave][ct][c * 68 + gp * 8];
        bf16x4 hi = *(const bf16x4*)&Ps[wave][ct][c * 68 + gp * 8 + 4];
        pa[ct][0] = lo[0]; pa[ct][1] = lo[1]; pa[ct][2] = lo[2]; pa[ct][3] = lo[3];
        pa[ct][4] = hi[0]; pa[ct][5] = hi[1]; pa[ct][6] = hi[2]; pa[ct][7] = hi[3];
      }
      #pragma unroll
      for (int nt = 0; nt < 4; ++nt) {
        bf16x8 vf = *(const bf16x8*)&Vs[cur][(nt * 16 + c) * 64 +
                                            ((((ch << 2) | quad) ^ (c & 7)) << 3)];
        #pragma unroll
        for (int ct = 0; ct < 2; ++ct)
          o[ct][nt] = MFMA(vf, pa[ct], o[ct][nt]);
      }
    }

    // ---- single drain + barrier per iter ----
    __asm__ volatile("s_waitcnt vmcnt(0) lgkmcnt(0)" ::: "memory");
    __builtin_amdgcn_s_barrier();
  }

  // ---- l reduce over the 4 quads sharing q, normalize, float4 store ----
  #pragma unroll
  for (int ct = 0; ct < 2; ++ct) {
    float l = lsum[ct];
    l += __shfl_xor(l, 16, 64);
    l += __shfl_xor(l, 32, 64);
    const float inv = 1.0f / l;
    const int srow = qblk * 128 + wave * 32 + ct * 16 + c;
    #pragma unroll
    for (int nt = 0; nt < 4; ++nt) {
      float4 st = { o[ct][nt][0] * inv, o[ct][nt][1] * inv,
                    o[ct][nt][2] * inv, o[ct][nt][3] * inv };
      *(float4*)&out[((size_t)b * 2048 + srow) * 1024 + h * 64 + nt * 16 + 4 * quad] = st;
    }
  }
}

// ---------------------------------------------------------------------------
extern "C" void kernel_launch(void* const* d_in, const int* in_sizes, int n_in,
                              void* d_out, int out_size, void* d_ws, size_t ws_size,
                              hipStream_t stream) {
  const float* hs   = (const float*)d_in[0];
  const float* mask = (const float*)d_in[1];
  const float* qw   = (const float*)d_in[2];
  const float* qb   = (const float*)d_in[3];
  const float* kw   = (const float*)d_in[4];
  const float* kb   = (const float*)d_in[5];
  const float* vw   = (const float*)d_in[6];
  const float* vb   = (const float*)d_in[7];
  float* out = (float*)d_out;

  bf16* Xb   = (bf16*)d_ws;                       // 4096x1024      (8 MB)
  bf16* Wt   = Xb + (size_t)4096 * 1024;          // 3x1024x1024    (6 MB)
  bf16* q_ws = Wt + (size_t)3 * 1048576;          // [B,H,S,64]     (8 MB)
  bf16* k_ws = q_ws + (size_t)4096 * 1024;        // [B,H,S,64]     (8 MB)
  bf16* v_ws = k_ws + (size_t)4096 * 1024;        // [B,H,64,S] V^T (8 MB)

  cvt<<<dim3(2816), 256, 0, stream>>>(hs, qw, kw, vw, Xb, Wt);
  qkv_gemm<<<dim3(768), 256, 0, stream>>>(Xb, Wt, qb, kb, vb, q_ws, k_ws, v_ws);
  attn<<<dim3(512), 256, 0, stream>>>(q_ws, k_ws, v_ws, mask, out);
}

// Round 3
// 163.777 us; speedup vs baseline: 1.0809x; 1.0799x over previous
//
#include <hip/hip_runtime.h>

typedef __bf16 bf16;
typedef __attribute__((ext_vector_type(8))) __bf16 bf16x8;
typedef __attribute__((ext_vector_type(4))) __bf16 bf16x4;
typedef __attribute__((ext_vector_type(4))) float f32x4;
typedef __attribute__((ext_vector_type(2))) unsigned int uint2v;
typedef __attribute__((ext_vector_type(4))) unsigned int uint4v;

#define MFMA(a, b, c) __builtin_amdgcn_mfma_f32_16x16x32_bf16((a), (b), (c), 0, 0, 0)
#define LOG2E 1.44269504088896340736f

__device__ __forceinline__ bf16x8 cvt8(float4 a, float4 b) {
  bf16x8 r;
  r[0] = (bf16)a.x; r[1] = (bf16)a.y; r[2] = (bf16)a.z; r[3] = (bf16)a.w;
  r[4] = (bf16)b.x; r[5] = (bf16)b.y; r[6] = (bf16)b.z; r[7] = (bf16)b.w;
  return r;
}

// async global->LDS, 16B per lane. LDS dest = wave-uniform base + lane*16.
__device__ __forceinline__ void stage16(const bf16* g, bf16* l) {
  __builtin_amdgcn_global_load_lds(
      (const __attribute__((address_space(1))) void*)g,
      (__attribute__((address_space(3))) void*)l, 16, 0, 0);
}

// ---------------------------------------------------------------------------
// Kernel 0: cast X -> bf16; cast+transpose W -> bf16 W^T[n][k] (3 matrices).
// ---------------------------------------------------------------------------
__global__ __launch_bounds__(256)
void cvt(const float* __restrict__ hs, const float* __restrict__ qw,
         const float* __restrict__ kw, const float* __restrict__ vw,
         bf16* __restrict__ Xb, bf16* __restrict__ Wt) {
  const int bid = blockIdx.x, tid = threadIdx.x;
  if (bid < 2048) {               // X: 4096x1024 fp32 -> bf16, 8 elems/thread
    size_t off = (size_t)bid * 2048 + tid * 8;
    float4 x0 = *(const float4*)(hs + off);
    float4 x1 = *(const float4*)(hs + off + 4);
    *(bf16x8*)(Xb + off) = cvt8(x0, x1);
  } else {                        // W transpose: 64x64 tiles via LDS
    int t = bid - 2048;           // 0..767
    int z = t >> 8, ti = t & 255;
    const float* W = (z == 0) ? qw : (z == 1) ? kw : vw;
    int k0 = (ti >> 4) * 64, n0 = (ti & 15) * 64;
    __shared__ bf16 T[64 * 72];   // [n][k], pad 72 (16B-aligned rows)
    #pragma unroll
    for (int i = 0; i < 16; ++i) {
      int e = i * 256 + tid;
      int kr = e >> 6, nc = e & 63;
      T[nc * 72 + kr] = (bf16)W[(size_t)(k0 + kr) * 1024 + n0 + nc];
    }
    __syncthreads();
    #pragma unroll
    for (int i = 0; i < 2; ++i) {
      int e = i * 256 + tid;
      int nr = e >> 3, kg = e & 7;
      *(bf16x8*)(Wt + (size_t)z * 1048576 + (size_t)(n0 + nr) * 1024 + k0 + kg * 8) =
          *(const bf16x8*)&T[nr * 72 + kg * 8];
    }
  }
}

// ---------------------------------------------------------------------------
// Kernel 1: QKV GEMM (m97-style). 128x128 tile, 4 waves 2x2, BK=64,
// global_load_lds w=16, XOR-granule swizzle on the global-address side.
// Q pre-scaled by 0.125*log2e. V written TRANSPOSED [B,H,64,S].
// ---------------------------------------------------------------------------
__global__ __launch_bounds__(256, 3)
void qkv_gemm(const bf16* __restrict__ Xb, const bf16* __restrict__ Wt,
              const float* __restrict__ qbias, const float* __restrict__ kbias,
              const float* __restrict__ vbias,
              bf16* __restrict__ qo, bf16* __restrict__ ko, bf16* __restrict__ vo) {
  const int blk = blockIdx.x;           // 0..767
  const int xcd = blk & 7, slot = blk >> 3;   // slot 0..95
  const int mb = xcd * 4 + slot / 24;   // 0..31 (mb-band per XCD)
  const int nb = slot % 24;             // 0..23
  const int z = nb >> 3, nbm = nb & 7;
  const bf16* W = Wt + (size_t)z * 1048576;

  const int tid = threadIdx.x;
  const int wave = tid >> 6, lane = tid & 63, quad = lane >> 4, c = lane & 15;
  const int wr = wave >> 1, wc = wave & 1;
  const int lrow = lane >> 3;                 // 0..7 within the 8-row group
  const int lg = (lane & 7) ^ lrow;           // swizzled source granule

  __shared__ bf16 As[128 * 64];               // [m][k], granule g at pos g^(m&7)
  __shared__ bf16 Bs[128 * 64];               // [n][k], same swizzle

  f32x4 acc[4][4] = {};

  for (int k0 = 0; k0 < 1024; k0 += 64) {
    #pragma unroll
    for (int i = 0; i < 4; ++i) {
      int r = wave * 32 + i * 8;              // base row (mult of 8)
      stage16(Xb + (size_t)(mb * 128 + r + lrow) * 1024 + k0 + lg * 8, &As[r * 64]);
      stage16(W + (size_t)(nbm * 128 + r + lrow) * 1024 + k0 + lg * 8, &Bs[r * 64]);
    }
    __syncthreads();
    #pragma unroll
    for (int ch = 0; ch < 2; ++ch) {
      bf16x8 af[4];
      #pragma unroll
      for (int rt = 0; rt < 4; ++rt) {
        int row = wr * 64 + rt * 16 + c;      // row&7 == c&7
        af[rt] = *(const bf16x8*)&As[row * 64 + ((((ch << 2) | quad) ^ (c & 7)) << 3)];
      }
      #pragma unroll
      for (int nt = 0; nt < 4; ++nt) {
        int row = wc * 64 + nt * 16 + c;
        bf16x8 bfrag = *(const bf16x8*)&Bs[row * 64 + ((((ch << 2) | quad) ^ (c & 7)) << 3)];
        #pragma unroll
        for (int rt = 0; rt < 4; ++rt)
          acc[rt][nt] = MFMA(af[rt], bfrag, acc[rt][nt]);
      }
    }
    __syncthreads();
  }

  const float* bias = (z == 0) ? qbias : (z == 1) ? kbias : vbias;
  float bv[4];
  #pragma unroll
  for (int nt = 0; nt < 4; ++nt)
    bv[nt] = bias[nbm * 128 + wc * 64 + nt * 16 + c];

  if (z == 2) {
    // V^T: vo[((b*16+h)*64 + d)*2048 + s], packed 4 along s (= reg dim)
    #pragma unroll
    for (int rt = 0; rt < 4; ++rt)
      #pragma unroll
      for (int nt = 0; nt < 4; ++nt) {
        int m0 = mb * 128 + wr * 64 + rt * 16 + 4 * quad;
        int n = nbm * 128 + wc * 64 + nt * 16 + c;
        bf16x4 pk;
        #pragma unroll
        for (int reg = 0; reg < 4; ++reg) pk[reg] = (bf16)(acc[rt][nt][reg] + bv[nt]);
        int b = m0 >> 11, s0 = m0 & 2047, h = n >> 6, d = n & 63;
        *(bf16x4*)&vo[(((size_t)b * 16 + h) * 64 + d) * 2048 + s0] = pk;
      }
  } else {
    bf16* dst = (z == 0) ? qo : ko;
    const float scale = (z == 0) ? 0.125f * LOG2E : 1.0f;  // fold 1/sqrt(d)*log2e into Q
    #pragma unroll
    for (int rt = 0; rt < 4; ++rt)
      #pragma unroll
      for (int nt = 0; nt < 4; ++nt)
        #pragma unroll
        for (int reg = 0; reg < 4; ++reg) {
          float v = (acc[rt][nt][reg] + bv[nt]) * scale;
          int m = mb * 128 + wr * 64 + rt * 16 + 4 * quad + reg;
          int n = nbm * 128 + wc * 64 + nt * 16 + c;
          int b = m >> 11, s = m & 2047, h = n >> 6, d = n & 63;
          dst[(((size_t)b * 16 + h) * 2048 + s) * 64 + d] = (bf16)v;
        }
  }
}

// ---------------------------------------------------------------------------
// Kernel 2: attention. Latency-chain attack (rounds 1-2 showed all pipes idle,
// ~5300 cyc/iter invariant):
//  - triple-buffered K/V + counted s_waitcnt vmcnt(4): stage tile k+2 at top
//    of iter k; loads get ~2 iterations to land. vmcnt(0) only in peeled last
//    iteration. No vmcnt(0)+barrier convoy in the main loop.
//  - P never touches LDS: quad-transpose in registers via
//    (P0,P2)=permlane16_swap(permlane32_swap(X0,Y0)) on packed bf16 dwords.
//    Replaces ds_write+lgkmcnt(0)+ds_read round-trip (~300 cyc/iter).
//  - mask staged to LDS pre-scaled by log2e in prologue: zero in-loop global
//    loads besides staging -> vmcnt counts are exact.
//  - s_setprio(1) around MFMA clusters (waves now phase-diverse).
// Geometry unchanged: 4 waves x 32 q-rows, 512 WGs, 2 WG/CU. LDS 56KB.
// ---------------------------------------------------------------------------
__global__ __launch_bounds__(256, 2)
void attn(const bf16* __restrict__ qg, const bf16* __restrict__ kg,
          const bf16* __restrict__ vtg, const float* __restrict__ mask,
          float* __restrict__ out) {
  const int blk = blockIdx.x;                // 0..511
  const int xcd = blk & 7, slot = blk >> 3;  // slot 0..63
  const int bh = xcd * 4 + (slot >> 4);      // 4 bh per XCD (K/V pinned in L2)
  const int qblk = slot & 15;                // 16 qblks x 128 rows
  const int b = bh >> 4, h = bh & 15;
  const int tid = threadIdx.x;
  const int wave = tid >> 6, lane = tid & 63, quad = lane >> 4, c = lane & 15;
  const int lrow = lane >> 3, lg = (lane & 7) ^ lrow;

  __shared__ __align__(16) bf16 Ks[3][64 * 64];  // [key][d], granule swizzle
  __shared__ __align__(16) bf16 Vs[3][64 * 64];  // [d][key], granule swizzle
  __shared__ __align__(16) float Ms[2048];       // mask*log2e

  const bf16* qb_ = qg + (size_t)bh * 2048 * 64;
  const bf16* kb_ = kg + (size_t)bh * 2048 * 64;
  const bf16* vb_ = vtg + (size_t)bh * 64 * 2048;

  // ---- prologue: mask -> LDS (pre-scaled), Q frags, stage tiles 0 and 1 ----
  #pragma unroll
  for (int i = 0; i < 2; ++i) {
    int idx = i * 1024 + tid * 4;
    float4 m = *(const float4*)&mask[b * 2048 + idx];
    float4 ms = {m.x * LOG2E, m.y * LOG2E, m.z * LOG2E, m.w * LOG2E};
    *(float4*)&Ms[idx] = ms;
  }

  bf16x8 qf[2][2];   // Q pre-scaled by 0.125*log2e; wave owns rows wave*32+ct*16+c
  #pragma unroll
  for (int ct = 0; ct < 2; ++ct)
    #pragma unroll
    for (int ch = 0; ch < 2; ++ch)
      qf[ct][ch] = *(const bf16x8*)(qb_ +
          (size_t)(qblk * 128 + wave * 32 + ct * 16 + c) * 64 + ch * 32 + quad * 8);

  #pragma unroll
  for (int t = 0; t < 2; ++t) {
    #pragma unroll
    for (int i = 0; i < 2; ++i) {
      int r = wave * 16 + i * 8;
      stage16(kb_ + (size_t)(t * 64 + r + lrow) * 64 + lg * 8, &Ks[t][r * 64]);
      stage16(vb_ + (size_t)(r + lrow) * 2048 + t * 64 + lg * 8, &Vs[t][r * 64]);
    }
    __builtin_amdgcn_sched_barrier(0);   // keep tile-0 batch older than tile-1
  }
  __asm__ volatile("s_waitcnt lgkmcnt(0)" ::: "memory");  // mask ds_writes done

  f32x4 o[2][4] = {};     // o[ct][nt][reg] = O[q=ct*16+c][d=nt*16+4*quad+reg]
  float lsum[2] = {0.f, 0.f};

  int cur = 0;
  for (int kt = 0; kt < 32; ++kt) {
    // tile kt ready when only the newest 4 staging loads (tile kt+1) remain
    if (kt < 31) { __asm__ volatile("s_waitcnt vmcnt(4)" ::: "memory"); }
    else         { __asm__ volatile("s_waitcnt vmcnt(0)" ::: "memory"); }
    __builtin_amdgcn_s_barrier();
    __builtin_amdgcn_sched_barrier(0);   // nothing hoists above the barrier

    if (kt < 30) {                       // stage tile kt+2 into buffer (cur+2)%3
      int stg = cur - 1; if (stg < 0) stg = 2;
      #pragma unroll
      for (int i = 0; i < 2; ++i) {
        int r = wave * 16 + i * 8;
        stage16(kb_ + (size_t)((kt + 2) * 64 + r + lrow) * 64 + lg * 8,
                &Ks[stg][r * 64]);
        stage16(vb_ + (size_t)(r + lrow) * 2048 + (kt + 2) * 64 + lg * 8,
                &Vs[stg][r * 64]);
      }
    }
    __builtin_amdgcn_sched_barrier(0);   // staging issued before compute

    // ---- S^T = K Q^T ----
    f32x4 s[2][4] = {};
    __builtin_amdgcn_s_setprio(1);
    #pragma unroll
    for (int nt = 0; nt < 4; ++nt)
      #pragma unroll
      for (int ch = 0; ch < 2; ++ch) {
        bf16x8 kf = *(const bf16x8*)&Ks[cur][(nt * 16 + c) * 64 +
                                            ((((ch << 2) | quad) ^ (c & 7)) << 3)];
        s[0][nt] = MFMA(kf, qf[0][ch], s[0][nt]);
        s[1][nt] = MFMA(kf, qf[1][ch], s[1][nt]);
      }
    __builtin_amdgcn_s_setprio(0);

    float4 mv[4];
    #pragma unroll
    for (int nt = 0; nt < 4; ++nt)
      mv[nt] = *(const float4*)&Ms[kt * 64 + nt * 16 + 4 * quad];

    // ---- p = exp2(s + m'); pack to bf16 dwords; quad-transpose in regs ----
    // Lane(quad,c) holds P[key=nt*16+4*quad+reg][q=c]; PV needs
    // P[key=ch*32+8*quad..+7][q=c]. (P0,P2)=pl16swap(pl32swap(X0,Y0)) etc.
    bf16x8 pa[2][2];
    #pragma unroll
    for (int ct = 0; ct < 2; ++ct) {
      unsigned int U[4][2];
      #pragma unroll
      for (int nt = 0; nt < 4; ++nt) {
        bf16x4 pk;
        #pragma unroll
        for (int reg = 0; reg < 4; ++reg) {
          float mreg = (reg == 0) ? mv[nt].x : (reg == 1) ? mv[nt].y
                     : (reg == 2) ? mv[nt].z : mv[nt].w;
          float p = __builtin_amdgcn_exp2f(s[ct][nt][reg] + mreg);
          lsum[ct] += p;
          pk[reg] = (bf16)p;
        }
        uint2v uu = __builtin_bit_cast(uint2v, pk);
        U[nt][0] = uu.x; U[nt][1] = uu.y;
      }
      #pragma unroll
      for (int ch = 0; ch < 2; ++ch) {
        unsigned int X0 = U[2 * ch][0],     X1 = U[2 * ch][1];
        unsigned int Y0 = U[2 * ch + 1][0], Y1 = U[2 * ch + 1][1];
        __asm__ volatile("v_permlane32_swap_b32 %0, %1" : "+v"(X0), "+v"(Y0));
        __asm__ volatile("v_permlane32_swap_b32 %0, %1" : "+v"(X1), "+v"(Y1));
        __asm__ volatile("v_permlane16_swap_b32 %0, %1" : "+v"(X0), "+v"(Y0));
        __asm__ volatile("v_permlane16_swap_b32 %0, %1" : "+v"(X1), "+v"(Y1));
        uint4v up = {X0, X1, Y0, Y1};
        pa[ct][ch] = __builtin_bit_cast(bf16x8, up);
      }
    }

    // ---- O^T += V^T P^T ----
    __builtin_amdgcn_s_setprio(1);
    #pragma unroll
    for (int ch = 0; ch < 2; ++ch)
      #pragma unroll
      for (int nt = 0; nt < 4; ++nt) {
        bf16x8 vf = *(const bf16x8*)&Vs[cur][(nt * 16 + c) * 64 +
                                            ((((ch << 2) | quad) ^ (c & 7)) << 3)];
        o[0][nt] = MFMA(vf, pa[0][ch], o[0][nt]);
        o[1][nt] = MFMA(vf, pa[1][ch], o[1][nt]);
      }
    __builtin_amdgcn_s_setprio(0);

    cur = (cur == 2) ? 0 : cur + 1;
  }

  // ---- l reduce over the 4 quads sharing q, normalize, float4 store ----
  #pragma unroll
  for (int ct = 0; ct < 2; ++ct) {
    float l = lsum[ct];
    l += __shfl_xor(l, 16, 64);
    l += __shfl_xor(l, 32, 64);
    const float inv = 1.0f / l;
    const int srow = qblk * 128 + wave * 32 + ct * 16 + c;
    #pragma unroll
    for (int nt = 0; nt < 4; ++nt) {
      float4 st = { o[ct][nt][0] * inv, o[ct][nt][1] * inv,
                    o[ct][nt][2] * inv, o[ct][nt][3] * inv };
      *(float4*)&out[((size_t)b * 2048 + srow) * 1024 + h * 64 + nt * 16 + 4 * quad] = st;
    }
  }
}

// ---------------------------------------------------------------------------
extern "C" void kernel_launch(void* const* d_in, const int* in_sizes, int n_in,
                              void* d_out, int out_size, void* d_ws, size_t ws_size,
                              hipStream_t stream) {
  const float* hs   = (const float*)d_in[0];
  const float* mask = (const float*)d_in[1];
  const float* qw   = (const float*)d_in[2];
  const float* qb   = (const float*)d_in[3];
  const float* kw   = (const float*)d_in[4];
  const float* kb   = (const float*)d_in[5];
  const float* vw   = (const float*)d_in[6];
  const float* vb   = (const float*)d_in[7];
  float* out = (float*)d_out;

  bf16* Xb   = (bf16*)d_ws;                       // 4096x1024      (8 MB)
  bf16* Wt   = Xb + (size_t)4096 * 1024;          // 3x1024x1024    (6 MB)
  bf16* q_ws = Wt + (size_t)3 * 1048576;          // [B,H,S,64]     (8 MB)
  bf16* k_ws = q_ws + (size_t)4096 * 1024;        // [B,H,S,64]     (8 MB)
  bf16* v_ws = k_ws + (size_t)4096 * 1024;        // [B,H,64,S] V^T (8 MB)

  cvt<<<dim3(2816), 256, 0, stream>>>(hs, qw, kw, vw, Xb, Wt);
  qkv_gemm<<<dim3(768), 256, 0, stream>>>(Xb, Wt, qb, kb, vb, q_ws, k_ws, v_ws);
  attn<<<dim3(512), 256, 0, stream>>>(q_ws, k_ws, v_ws, mask, out);
}